// Round 6
// baseline (27.003 us; speedup 1.0000x reference)
//
#include <hip/hip_runtime.h>
#include <hip/hip_bf16.h>

typedef _Float16 f16;
typedef f16 f16x2 __attribute__((ext_vector_type(2)));
typedef f16 f16x4 __attribute__((ext_vector_type(4)));
typedef f16 f16x8 __attribute__((ext_vector_type(8)));
typedef float f32x4 __attribute__((ext_vector_type(4)));

constexpr int B_  = 4;
constexpr int H_  = 128;
constexpr int W_  = 128;
constexpr int C_  = 64;
constexpr int NH_ = 4;
constexpr int D_  = 16;
constexpr int KK_ = 25;

constexpr int TW_  = 8, TH_ = 8;
constexpr int HWID = 12, HHEI = 12;
constexpr int NPX  = HHEI * HWID;        // 144 halo pixels
constexpr int RSTR = 72;                 // f16 per LDS pixel row (144 B)
constexpr int ABYTES = NPX * RSTR * 2;   // 20736  ref staging
constexpr int RBYTES = NPX * RSTR * 2;   // 20736  r output
constexpr int MBYTES = 64  * RSTR * 2;   // 9216   main staging
constexpr int QBYTES = 64  * RSTR * 2;   // 9216   q output
constexpr int AOFF = 0;
constexpr int ROFF = ABYTES;
constexpr int MOFF = ABYTES + RBYTES;
constexpr int QOFF = MOFF + MBYTES;      // 50688
constexpr int MSOFF = QOFF + QBYTES;     // 59904 (mbuf/sbuf, NOT aliased)
constexpr int SMEM  = MSOFF + 4096;      // 64000 -> 2 blocks/CU
constexpr int PSTRIDE = KK_ + 2;         // 27
constexpr int PSLAB  = 64 * PSTRIDE;     // 1728 f32

// W-fragment buffer: [2 tensors][4 heads][2 s][64 lanes][8 f16] = 16 KB
constexpr int FRAG_T = NH_ * 2 * 64 * 8;          // 4096 f16 per tensor
constexpr size_t FRAG_BYTES = 2 * FRAG_T * 2;     // 16384 B

#if __has_builtin(__builtin_amdgcn_fdot2)
#define FDOT2(a, b, c) __builtin_amdgcn_fdot2((a), (b), (c), false)
#else
#define FDOT2(a, b, c) fmaf((float)(a)[1], (float)(b)[1], fmaf((float)(a)[0], (float)(b)[0], (c)))
#endif

__device__ __forceinline__ int div12(int x) { return (x * 171) >> 11; }  // exact for 0..143

// ---------------------------------------------------------------------------
// Setup: pack W_main / W_ref into MFMA A-fragments (f16), coalesced for main.
// frag[t] layout, t = (n*2+s)*64 + l: e[i] = W[n][(s*32+kg*8+i)][row],
// row = l&15, kg = l>>4.  main frags at [0], ref frags at [FRAG_T].
// ---------------------------------------------------------------------------
__global__ __launch_bounds__(64) void wfrag_kernel(
    const float* __restrict__ wmain, const float* __restrict__ wref,
    f16* __restrict__ frag)
{
    const int t = blockIdx.x * 64 + threadIdx.x;   // 0..511
    const int n = t >> 7;
    const int s = (t >> 6) & 1;
    const int l = t & 63;
    const int row = l & 15, kg = l >> 4;
    union { f16x8 v; f16 e[8]; } um, ur;
    #pragma unroll
    for (int i = 0; i < 8; ++i) {
        int k = s * 32 + kg * 8 + i;
        um.e[i] = (f16)wmain[n * C_ * D_ + k * D_ + row];
        ur.e[i] = (f16)wref [n * C_ * D_ + k * D_ + row];
    }
    *(f16x8*)(frag + t * 8) = um.v;
    *(f16x8*)(frag + FRAG_T + t * 8) = ur.v;
}

// ---------------------------------------------------------------------------
// Main fused kernel. FRAG=true: weights from d_ws fragments (4 b128 loads).
// ---------------------------------------------------------------------------
template <bool FRAG>
__global__ __launch_bounds__(512, 4) void rl8mh6(
    const float* __restrict__ mainp, const float* __restrict__ refp,
    const float* __restrict__ wmain, const float* __restrict__ wref,
    const f16* __restrict__ wfrag, float* __restrict__ out)
{
    __shared__ __align__(16) unsigned char smraw[SMEM];
    f16*   abuf = (f16*)(smraw + AOFF);
    f16*   rbuf = (f16*)(smraw + ROFF);
    f16*   mabuf= (f16*)(smraw + MOFF);
    f16*   qbuf = (f16*)(smraw + QOFF);
    float* xbuf = (float*)smraw;                    // prob exchange (aliases abuf/rbuf, fenced)
    float* mbuf = (float*)(smraw + MSOFF);          // [2][4][64] partial max
    float* sbuf = (float*)(smraw + MSOFF + 2048);   // [2][4][64] partial sum

    const int tid = threadIdx.x;
    const int l   = tid & 63;
    const int wid = __builtin_amdgcn_readfirstlane(tid >> 6);  // 0..7
    const int n   = wid & 3;    // head
    const int h   = wid >> 2;   // half
    const int row = l & 15;
    const int kg  = l >> 4;

    const int x0 = blockIdx.x * TW_;
    const int y0 = blockIdx.y * TH_;
    const int b  = blockIdx.z;
    const float* mainb = mainp + ((size_t)b * H_) * W_ * C_;
    const float* refb  = refp  + ((size_t)b * H_) * W_ * C_;

    // ---- weight fragments for head n ----
    f16x8 bm[2], br[2];
    if (FRAG) {
        bm[0] = *(const f16x8*)(wfrag + ((n * 2 + 0) * 64 + l) * 8);
        bm[1] = *(const f16x8*)(wfrag + ((n * 2 + 1) * 64 + l) * 8);
        br[0] = *(const f16x8*)(wfrag + FRAG_T + ((n * 2 + 0) * 64 + l) * 8);
        br[1] = *(const f16x8*)(wfrag + FRAG_T + ((n * 2 + 1) * 64 + l) * 8);
    } else {
        const float* wm = wmain + n * C_ * D_;
        const float* wr = wref  + n * C_ * D_;
        #pragma unroll
        for (int s = 0; s < 2; ++s) {
            union { f16x8 v; f16 e[8]; } um, ur;
            #pragma unroll
            for (int i = 0; i < 8; ++i) {
                int k = s * 32 + kg * 8 + i;
                um.e[i] = (f16)wm[k * D_ + row];
                ur.e[i] = (f16)wr[k * D_ + row];
            }
            bm[s] = um.v; br[s] = ur.v;
        }
    }

    // ---- Phase 0: coalesced staging, f32 -> f16 once ----
    for (int j = tid; j < NPX * 16; j += 512) {
        int hp = j >> 4, c4 = j & 15;
        int hy = div12(hp), hx = hp - hy * HWID;
        int gy = y0 + hy - 2, gx = x0 + hx - 2;
        float4 v = make_float4(0.f, 0.f, 0.f, 0.f);
        if ((unsigned)gy < (unsigned)H_ && (unsigned)gx < (unsigned)W_)
            v = *(const float4*)(refb + ((size_t)gy * W_ + gx) * C_ + c4 * 4);
        f16x4 h4 = {(f16)v.x, (f16)v.y, (f16)v.z, (f16)v.w};
        *(f16x4*)(abuf + hp * RSTR + c4 * 4) = h4;
    }
    for (int j = tid; j < 64 * 16; j += 512) {
        int px = j >> 4, c4 = j & 15;
        int gy = y0 + (px >> 3), gx = x0 + (px & 7);
        float4 v = *(const float4*)(mainb + ((size_t)gy * W_ + gx) * C_ + c4 * 4);
        f16x4 h4 = {(f16)v.x, (f16)v.y, (f16)v.z, (f16)v.w};
        *(f16x4*)(mabuf + px * RSTR + c4 * 4) = h4;
    }
    __syncthreads();

    // ---- Projections, swapped operands: D[d][px], lane = one pixel ----
    auto do_rtile = [&](int t) {
        const f16* ap = abuf + (t * 16 + row) * RSTR + kg * 8;
        f16x8 B0 = *(const f16x8*)(ap);
        f16x8 B1 = *(const f16x8*)(ap + 32);
        f32x4 acc = {0.f, 0.f, 0.f, 0.f};
        acc = __builtin_amdgcn_mfma_f32_16x16x32_f16(br[0], B0, acc, 0, 0, 0);
        acc = __builtin_amdgcn_mfma_f32_16x16x32_f16(br[1], B1, acc, 0, 0, 0);
        int cpx = t * 16 + row;                    // this lane's pixel
        int key = (div12(cpx) & 7) * 8;
        f16x4 h4 = {(f16)acc[0], (f16)acc[1], (f16)acc[2], (f16)acc[3]};
        *(f16x4*)&rbuf[cpx * RSTR + ((n * 16 + kg * 4) ^ key)] = h4;
    };
    auto do_qtile = [&](int t) {
        const f16* ap = mabuf + (t * 16 + row) * RSTR + kg * 8;
        f16x8 B0 = *(const f16x8*)(ap);
        f16x8 B1 = *(const f16x8*)(ap + 32);
        f32x4 acc = {0.f, 0.f, 0.f, 0.f};
        acc = __builtin_amdgcn_mfma_f32_16x16x32_f16(bm[0], B0, acc, 0, 0, 0);
        acc = __builtin_amdgcn_mfma_f32_16x16x32_f16(bm[1], B1, acc, 0, 0, 0);
        int cpx = t * 16 + row;
        int key = ((cpx >> 3) & 7) * 8;
        f16x4 h4 = {(f16)acc[0], (f16)acc[1], (f16)acc[2], (f16)acc[3]};
        *(f16x4*)&qbuf[cpx * RSTR + ((n * 16 + kg * 4) ^ key)] = h4;
    };

    if (h == 0) { do_rtile(0); do_rtile(2); do_rtile(4); do_rtile(6); do_rtile(8);
                  do_qtile(0); do_qtile(2); }
    else        { do_rtile(1); do_rtile(3); do_rtile(5); do_rtile(7);
                  do_qtile(1); do_qtile(3); }

    __syncthreads();

    // ---- per-thread q fragment ----
    const int py  = l >> 3;
    const int pxx = l & 7;
    const int qkey = (py & 7) * 8;
    f16x8 q0 = *(const f16x8*)&qbuf[l * RSTR + ((n * 16 + 0) ^ qkey)];
    f16x8 q1 = *(const f16x8*)&qbuf[l * RSTR + ((n * 16 + 8) ^ qkey)];
    const f16x2* q2a = (const f16x2*)&q0;
    const f16x2* q2b = (const f16x2*)&q1;

    // ---- logits: half h computes 13 (or 12) offsets ----
    float lg[13];
    auto do_lg = [&](int idx, int k) {
        int ky = k / 5, kx = k % 5;              // compile-time
        int hy = py + ky;
        int key = (hy & 7) * 8;
        const f16* rp = &rbuf[(hy * 12 + pxx + kx) * RSTR];
        f16x8 r0 = *(const f16x8*)&rp[(n * 16 + 0) ^ key];
        f16x8 r1 = *(const f16x8*)&rp[(n * 16 + 8) ^ key];
        const f16x2* r2a = (const f16x2*)&r0;
        const f16x2* r2b = (const f16x2*)&r1;
        float a = 0.f;
        #pragma unroll
        for (int j = 0; j < 4; ++j) a = FDOT2(q2a[j], r2a[j], a);
        #pragma unroll
        for (int j = 0; j < 4; ++j) a = FDOT2(q2b[j], r2b[j], a);
        lg[idx] = a;
    };
    if (h == 0) {
        do_lg(0,0);  do_lg(1,1);  do_lg(2,2);  do_lg(3,3);  do_lg(4,4);
        do_lg(5,5);  do_lg(6,6);  do_lg(7,7);  do_lg(8,8);  do_lg(9,9);
        do_lg(10,10); do_lg(11,11); do_lg(12,12);
    } else {
        do_lg(0,13); do_lg(1,14); do_lg(2,15); do_lg(3,16); do_lg(4,17);
        do_lg(5,18); do_lg(6,19); do_lg(7,20); do_lg(8,21); do_lg(9,22);
        do_lg(10,23); do_lg(11,24);
        lg[12] = -1e30f;   // dead slot -> exp()=0
    }

    // ---- split softmax ----
    float mloc = lg[0];
    #pragma unroll
    for (int k = 1; k < 13; ++k) mloc = fmaxf(mloc, lg[k]);
    mbuf[(h * 4 + n) * 64 + l] = mloc;
    __syncthreads();
    float mo = mbuf[((1 - h) * 4 + n) * 64 + l];
    float m  = fmaxf(mloc, mo);

    float s = 0.f;
    #pragma unroll
    for (int k = 0; k < 13; ++k) { lg[k] = __expf(lg[k] - m); s += lg[k]; }
    sbuf[(h * 4 + n) * 64 + l] = s;
    __syncthreads();
    float so  = sbuf[((1 - h) * 4 + n) * 64 + l];
    float inv = 1.0f / (s + so);

    // ---- write probs (xbuf aliases abuf/rbuf; all rbuf reads done pre-S3) ----
    const int k0 = h * 13;
    #pragma unroll
    for (int k = 0; k < 13; ++k) {
        if (k0 + k < KK_)
            xbuf[n * PSLAB + l * PSTRIDE + (k0 + k)] = lg[k] * inv;
    }
    __syncthreads();

    // ---- head-average + store ----
    for (int i = tid; i < TW_ * TH_ * KK_; i += 512) {
        int p2 = i / KK_;
        int k  = i - p2 * KK_;
        int off = p2 * PSTRIDE + k;
        float v = 0.25f * (xbuf[off] + xbuf[PSLAB + off] + xbuf[2 * PSLAB + off] + xbuf[3 * PSLAB + off]);
        out[(((size_t)b * H_ + (y0 + (p2 >> 3))) * W_ + (x0 + (p2 & 7))) * KK_ + k] = v;
    }
}

extern "C" void kernel_launch(void* const* d_in, const int* in_sizes, int n_in,
                              void* d_out, int out_size, void* d_ws, size_t ws_size,
                              hipStream_t stream) {
    const float* mainp = (const float*)d_in[0];
    const float* refp  = (const float*)d_in[1];
    const float* wmain = (const float*)d_in[2];
    const float* wref  = (const float*)d_in[3];
    float* outp = (float*)d_out;

    dim3 grid(W_ / TW_, H_ / TH_, B_);
    if (ws_size >= FRAG_BYTES) {
        f16* frag = (f16*)d_ws;
        wfrag_kernel<<<dim3(8), dim3(64), 0, stream>>>(wmain, wref, frag);
        rl8mh6<true><<<grid, dim3(512), 0, stream>>>(mainp, refp, wmain, wref, frag, outp);
    } else {
        rl8mh6<false><<<grid, dim3(512), 0, stream>>>(mainp, refp, wmain, wref, nullptr, outp);
    }
}

// Round 7
// 19.779 us; speedup vs baseline: 1.3653x; 1.3653x over previous
//
#include <hip/hip_runtime.h>
#include <hip/hip_bf16.h>

typedef _Float16 f16;
typedef f16 f16x2 __attribute__((ext_vector_type(2)));
typedef f16 f16x4 __attribute__((ext_vector_type(4)));
typedef f16 f16x8 __attribute__((ext_vector_type(8)));
typedef float f32x4 __attribute__((ext_vector_type(4)));

constexpr int B_  = 4;
constexpr int H_  = 128;
constexpr int W_  = 128;
constexpr int C_  = 64;
constexpr int NH_ = 4;
constexpr int D_  = 16;
constexpr int KK_ = 25;

constexpr int TW_  = 8, TH_ = 8;
constexpr int HWID = 12, HHEI = 12;
constexpr int NPX  = HHEI * HWID;          // 144 halo pixels
// LDS layout (tight, 16B-chunk XOR swizzled, stride 64 f16 = 128 B per pixel):
//   [0      , 18432) abuf  [144][64] f16  -> becomes rbuf after bar2/bar3
//   [18432  , 26624) mabuf [64][64]  f16  -> becomes qbuf
//   [0      , 27648) xbuf  (f32 prob exchange, aliases the above, fenced)
//   [27648  , 29696) mxbuf [2][4][64] f32 partial max
//   [29696  , 31744) smbuf [2][4][64] f32 partial sum
constexpr int MOFF  = NPX * 64 * 2;        // 18432
constexpr int MXOFF = 27648;
constexpr int SMOFF = 29696;
constexpr int SMEM  = 31744;               // < 40960 -> 4 blocks/CU (wave cap)
constexpr int PSTRIDE = KK_ + 2;           // 27
constexpr int PSLAB   = 64 * PSTRIDE;      // 1728 f32; 4 slabs = 27648 B

#if __has_builtin(__builtin_amdgcn_fdot2)
#define FDOT2(a, b, c) __builtin_amdgcn_fdot2((a), (b), (c), false)
#else
#define FDOT2(a, b, c) fmaf((float)(a)[1], (float)(b)[1], fmaf((float)(a)[0], (float)(b)[0], (c)))
#endif

__device__ __forceinline__ int div12(int x) { return (x * 171) >> 11; }  // exact for 0..143

__global__ __launch_bounds__(512, 8) void rl8mh7(
    const float* __restrict__ mainp, const float* __restrict__ refp,
    const float* __restrict__ wmain, const float* __restrict__ wref,
    float* __restrict__ out)
{
    __shared__ __align__(16) unsigned char smraw[SMEM];
    f16*   abuf  = (f16*)smraw;             // staged ref halo -> rbuf
    f16*   mabuf = (f16*)(smraw + MOFF);    // staged main     -> qbuf
    float* xbuf  = (float*)smraw;
    float* mxbuf = (float*)(smraw + MXOFF);
    float* smbuf = (float*)(smraw + SMOFF);

    const int tid = threadIdx.x;
    const int l   = tid & 63;
    const int wid = __builtin_amdgcn_readfirstlane(tid >> 6);  // 0..7
    const int n   = wid & 3;    // head
    const int h   = wid >> 2;   // half
    const int row = l & 15;
    const int kg  = l >> 4;

    const int x0 = blockIdx.x * TW_;
    const int y0 = blockIdx.y * TH_;
    const int b  = blockIdx.z;
    const float* mainb = mainp + ((size_t)b * H_) * W_ * C_;
    const float* refb  = refp  + ((size_t)b * H_) * W_ * C_;

    // ---- weight fragments for head n (A-operand of swapped MFMA) ----
    f16x8 am[2], ar[2];
    {
        const float* wm = wmain + n * C_ * D_;
        const float* wr = wref  + n * C_ * D_;
        #pragma unroll
        for (int s = 0; s < 2; ++s) {
            union { f16x8 v; f16 e[8]; } um, ur;
            #pragma unroll
            for (int i = 0; i < 8; ++i) {
                int k = s * 32 + kg * 8 + i;
                um.e[i] = (f16)wm[k * D_ + row];
                ur.e[i] = (f16)wr[k * D_ + row];
            }
            am[s] = um.v; ar[s] = ur.v;
        }
    }

    // ---- Phase 0: coalesced staging, f32 -> f16, 16B-chunk XOR swizzle ----
    for (int j = tid; j < NPX * 16; j += 512) {
        int hp = j >> 4, c4 = j & 15;
        int hy = div12(hp), hx = hp - hy * HWID;
        int gy = y0 + hy - 2, gx = x0 + hx - 2;
        float4 v = make_float4(0.f, 0.f, 0.f, 0.f);
        if ((unsigned)gy < (unsigned)H_ && (unsigned)gx < (unsigned)W_)
            v = *(const float4*)(refb + ((size_t)gy * W_ + gx) * C_ + c4 * 4);
        f16x4 h4 = {(f16)v.x, (f16)v.y, (f16)v.z, (f16)v.w};
        int off = hp * 64 + ((((c4 >> 1) ^ (hp & 7)) << 3) | ((c4 & 1) << 2));
        *(f16x4*)(abuf + off) = h4;
    }
    for (int j = tid; j < 64 * 16; j += 512) {
        int px = j >> 4, c4 = j & 15;
        int gy = y0 + (px >> 3), gx = x0 + (px & 7);
        float4 v = *(const float4*)(mainb + ((size_t)gy * W_ + gx) * C_ + c4 * 4);
        f16x4 h4 = {(f16)v.x, (f16)v.y, (f16)v.z, (f16)v.w};
        int off = px * 64 + ((((c4 >> 1) ^ (px & 7)) << 3) | ((c4 & 1) << 2));
        *(f16x4*)(mabuf + off) = h4;
    }
    __syncthreads();   // bar1

    // ---- Phase 1: projections into REGISTERS (swapped MFMA: lane = pixel) ----
    auto proj = [&](const f16* src, int t, const f16x8* A) -> f16x4 {
        int px = t * 16 + row;
        const f16* rp = src + px * 64;
        f16x8 B0 = *(const f16x8*)(rp + (((kg     ^ (px & 7)) << 3)));
        f16x8 B1 = *(const f16x8*)(rp + ((((kg+4) ^ (px & 7)) << 3)));
        f32x4 acc = {0.f, 0.f, 0.f, 0.f};
        acc = __builtin_amdgcn_mfma_f32_16x16x32_f16(A[0], B0, acc, 0, 0, 0);
        acc = __builtin_amdgcn_mfma_f32_16x16x32_f16(A[1], B1, acc, 0, 0, 0);
        return f16x4{(f16)acc[0], (f16)acc[1], (f16)acc[2], (f16)acc[3]};
    };
    f16x4 racc0, racc1, racc2, racc3, racc4, qacc0, qacc1;
    if (h == 0) {
        racc0 = proj(abuf, 0, ar); racc1 = proj(abuf, 2, ar);
        racc2 = proj(abuf, 4, ar); racc3 = proj(abuf, 6, ar);
        racc4 = proj(abuf, 8, ar);
        qacc0 = proj(mabuf, 0, am); qacc1 = proj(mabuf, 2, am);
    } else {
        racc0 = proj(abuf, 1, ar); racc1 = proj(abuf, 3, ar);
        racc2 = proj(abuf, 5, ar); racc3 = proj(abuf, 7, ar);
        qacc0 = proj(mabuf, 1, am); qacc1 = proj(mabuf, 3, am);
    }
    __syncthreads();   // bar2: all staging reads done -> safe to overwrite

    // ---- Phase 2: write r/q into the SAME buffers (lane holds d = kg*4..+3) ----
    auto wrout = [&](f16* dst, int t, f16x4 v) {
        int px = t * 16 + row;
        int c16 = (n << 1) | (kg >> 1);
        int off = px * 64 + (((c16 ^ (px & 7)) << 3) | ((kg & 1) << 2));
        *(f16x4*)(dst + off) = v;
    };
    if (h == 0) {
        wrout(abuf, 0, racc0); wrout(abuf, 2, racc1); wrout(abuf, 4, racc2);
        wrout(abuf, 6, racc3); wrout(abuf, 8, racc4);
        wrout(mabuf, 0, qacc0); wrout(mabuf, 2, qacc1);
    } else {
        wrout(abuf, 1, racc0); wrout(abuf, 3, racc1); wrout(abuf, 5, racc2);
        wrout(abuf, 7, racc3);
        wrout(mabuf, 1, qacc0); wrout(mabuf, 3, qacc1);
    }
    __syncthreads();   // bar3

    // ---- per-thread q fragment (pixel = lane) ----
    const int py  = l >> 3;
    const int pxx = l & 7;
    f16x8 q0 = *(const f16x8*)(mabuf + l * 64 + ((((n << 1) | 0) ^ (l & 7)) << 3));
    f16x8 q1 = *(const f16x8*)(mabuf + l * 64 + ((((n << 1) | 1) ^ (l & 7)) << 3));
    const f16x2* q2a = (const f16x2*)&q0;
    const f16x2* q2b = (const f16x2*)&q1;

    // ---- logits: half h computes 13 (or 12) offsets ----
    float lg[13];
    auto do_lg = [&](int idx, int k) {
        int ky = k / 5, kx = k % 5;              // compile-time
        int np = (py + ky) * 12 + pxx + kx;      // neighbor halo pixel
        const f16* rp = abuf + np * 64;
        f16x8 r0 = *(const f16x8*)(rp + ((((n << 1) | 0) ^ (np & 7)) << 3));
        f16x8 r1 = *(const f16x8*)(rp + ((((n << 1) | 1) ^ (np & 7)) << 3));
        const f16x2* r2a = (const f16x2*)&r0;
        const f16x2* r2b = (const f16x2*)&r1;
        float a = 0.f;
        #pragma unroll
        for (int j = 0; j < 4; ++j) a = FDOT2(q2a[j], r2a[j], a);
        #pragma unroll
        for (int j = 0; j < 4; ++j) a = FDOT2(q2b[j], r2b[j], a);
        lg[idx] = a;
    };
    if (h == 0) {
        do_lg(0,0);  do_lg(1,1);  do_lg(2,2);  do_lg(3,3);  do_lg(4,4);
        do_lg(5,5);  do_lg(6,6);  do_lg(7,7);  do_lg(8,8);  do_lg(9,9);
        do_lg(10,10); do_lg(11,11); do_lg(12,12);
    } else {
        do_lg(0,13); do_lg(1,14); do_lg(2,15); do_lg(3,16); do_lg(4,17);
        do_lg(5,18); do_lg(6,19); do_lg(7,20); do_lg(8,21); do_lg(9,22);
        do_lg(10,23); do_lg(11,24);
        lg[12] = -1e30f;   // dead slot -> exp()=0
    }

    // ---- split softmax: exchange max and sum ----
    float mloc = lg[0];
    #pragma unroll
    for (int k = 1; k < 13; ++k) mloc = fmaxf(mloc, lg[k]);
    mxbuf[(h * 4 + n) * 64 + l] = mloc;
    __syncthreads();   // bar4
    float mo = mxbuf[((1 - h) * 4 + n) * 64 + l];
    float m  = fmaxf(mloc, mo);

    float s = 0.f;
    #pragma unroll
    for (int k = 0; k < 13; ++k) { lg[k] = __expf(lg[k] - m); s += lg[k]; }
    smbuf[(h * 4 + n) * 64 + l] = s;
    __syncthreads();   // bar5
    float so  = smbuf[((1 - h) * 4 + n) * 64 + l];
    float inv = 1.0f / (s + so);

    // ---- write probs (xbuf aliases abuf/mabuf; all reads fenced by bar4/bar5) ----
    const int k0 = h * 13;
    #pragma unroll
    for (int k = 0; k < 13; ++k) {
        if (k0 + k < KK_)
            xbuf[n * PSLAB + l * PSTRIDE + (k0 + k)] = lg[k] * inv;
    }
    __syncthreads();   // bar6

    // ---- head-average + store ----
    for (int i = tid; i < TW_ * TH_ * KK_; i += 512) {
        int p2 = i / KK_;
        int k  = i - p2 * KK_;
        int off = p2 * PSTRIDE + k;
        float v = 0.25f * (xbuf[off] + xbuf[PSLAB + off] + xbuf[2 * PSLAB + off] + xbuf[3 * PSLAB + off]);
        out[(((size_t)b * H_ + (y0 + (p2 >> 3))) * W_ + (x0 + (p2 & 7))) * KK_ + k] = v;
    }
}

extern "C" void kernel_launch(void* const* d_in, const int* in_sizes, int n_in,
                              void* d_out, int out_size, void* d_ws, size_t ws_size,
                              hipStream_t stream) {
    const float* mainp = (const float*)d_in[0];
    const float* refp  = (const float*)d_in[1];
    const float* wmain = (const float*)d_in[2];
    const float* wref  = (const float*)d_in[3];
    float* outp = (float*)d_out;

    dim3 grid(W_ / TW_, H_ / TH_, B_);
    rl8mh7<<<grid, dim3(512), 0, stream>>>(mainp, refp, wmain, wref, outp);
}

// Round 8
// 18.876 us; speedup vs baseline: 1.4305x; 1.0478x over previous
//
#include <hip/hip_runtime.h>
#include <hip/hip_bf16.h>

typedef _Float16 f16;
typedef f16 f16x2 __attribute__((ext_vector_type(2)));
typedef f16 f16x4 __attribute__((ext_vector_type(4)));
typedef f16 f16x8 __attribute__((ext_vector_type(8)));
typedef float f32x4 __attribute__((ext_vector_type(4)));

constexpr int B_  = 4;
constexpr int H_  = 128;
constexpr int W_  = 128;
constexpr int C_  = 64;
constexpr int NH_ = 4;
constexpr int D_  = 16;
constexpr int KK_ = 25;

constexpr int TW_  = 8, TH_ = 8;
constexpr int HWID = 12, HHEI = 12;
constexpr int NPX  = HHEI * HWID;          // 144 halo pixels
// LDS layout (tight, 16B-chunk XOR swizzled, stride 64 f16 = 128 B per pixel):
//   [0      , 18432) abuf  [144][64] f16  -> becomes rbuf in-place
//   [18432  , 26624) mabuf [64][64]  f16  -> becomes qbuf in-place
//   [0      , 27648) xbuf  (f32 prob exchange, aliases the above, fenced)
//   [27648  , 31744) msbuf [2][4][64] float2 (m_loc, s_loc) exchange
constexpr int MOFF  = NPX * 64 * 2;        // 18432
constexpr int MSOFF = 27648;
constexpr int SMEM  = 31744;               // < 40960 -> 4 blocks/CU (wave cap)
constexpr int PSTRIDE = KK_ + 2;           // 27
constexpr int PSLAB   = 64 * PSTRIDE;      // 1728 f32; 4 slabs = 27648 B

#if __has_builtin(__builtin_amdgcn_fdot2)
#define FDOT2(a, b, c) __builtin_amdgcn_fdot2((a), (b), (c), false)
#else
#define FDOT2(a, b, c) fmaf((float)(a)[1], (float)(b)[1], fmaf((float)(a)[0], (float)(b)[0], (c)))
#endif

__device__ __forceinline__ int div12(int x) { return (x * 171) >> 11; }  // exact for 0..143

__global__ __launch_bounds__(512, 8) void rl8mh8(
    const float* __restrict__ mainp, const float* __restrict__ refp,
    const float* __restrict__ wmain, const float* __restrict__ wref,
    float* __restrict__ out)
{
    __shared__ __align__(16) unsigned char smraw[SMEM];
    f16*    abuf  = (f16*)smraw;             // staged ref halo -> rbuf
    f16*    mabuf = (f16*)(smraw + MOFF);    // staged main     -> qbuf
    float*  xbuf  = (float*)smraw;
    float2* msbuf = (float2*)(smraw + MSOFF);

    const int tid = threadIdx.x;
    const int l   = tid & 63;
    const int wid = __builtin_amdgcn_readfirstlane(tid >> 6);  // 0..7
    const int n   = wid & 3;    // head
    const int h   = wid >> 2;   // half
    const int row = l & 15;
    const int kg  = l >> 4;

    // XCD-chunked swizzle: consecutive dispatch%8 groups own 2-row spatial bands
    const int bid = blockIdx.y * 16 + blockIdx.x;      // 0..255 per z
    const int swz = (bid & 7) * 32 + (bid >> 3);       // bijective (256%8==0)
    const int x0 = (swz & 15) * TW_;
    const int y0 = (swz >> 4) * TH_;
    const int b  = blockIdx.z;
    const float* mainb = mainp + ((size_t)b * H_) * W_ * C_;
    const float* refb  = refp  + ((size_t)b * H_) * W_ * C_;

    // ---- Phase 0: coalesced staging, f32 -> f16, 16B-chunk XOR swizzle ----
    for (int j = tid; j < NPX * 16; j += 512) {
        int hp = j >> 4, c4 = j & 15;
        int hy = div12(hp), hx = hp - hy * HWID;
        int gy = y0 + hy - 2, gx = x0 + hx - 2;
        float4 v = make_float4(0.f, 0.f, 0.f, 0.f);
        if ((unsigned)gy < (unsigned)H_ && (unsigned)gx < (unsigned)W_)
            v = *(const float4*)(refb + ((size_t)gy * W_ + gx) * C_ + c4 * 4);
        f16x4 h4 = {(f16)v.x, (f16)v.y, (f16)v.z, (f16)v.w};
        int off = hp * 64 + ((((c4 >> 1) ^ (hp & 7)) << 3) | ((c4 & 1) << 2));
        *(f16x4*)(abuf + off) = h4;
    }
    for (int j = tid; j < 64 * 16; j += 512) {
        int px = j >> 4, c4 = j & 15;
        int gy = y0 + (px >> 3), gx = x0 + (px & 7);
        float4 v = *(const float4*)(mainb + ((size_t)gy * W_ + gx) * C_ + c4 * 4);
        f16x4 h4 = {(f16)v.x, (f16)v.y, (f16)v.z, (f16)v.w};
        int off = px * 64 + ((((c4 >> 1) ^ (px & 7)) << 3) | ((c4 & 1) << 2));
        *(f16x4*)(mabuf + off) = h4;
    }
    __syncthreads();   // bar1

    // ---- weight fragment build (A-operand of swapped MFMA), AFTER staging ----
    auto build_w = [&](const float* wsrc, f16x8* A) {
        const float* w = wsrc + n * C_ * D_;
        #pragma unroll
        for (int s = 0; s < 2; ++s) {
            union { f16x8 v; f16 e[8]; } u;
            #pragma unroll
            for (int i = 0; i < 8; ++i)
                u.e[i] = (f16)w[(s * 32 + kg * 8 + i) * D_ + row];
            A[s] = u.v;
        }
    };

    // ---- Phase 1: projections into registers (swapped MFMA: lane = pixel) ----
    auto proj = [&](const f16* src, int t, const f16x8* A) -> f16x4 {
        int px = t * 16 + row;
        const f16* rp = src + px * 64;
        f16x8 B0 = *(const f16x8*)(rp + (((kg     ^ (px & 7)) << 3)));
        f16x8 B1 = *(const f16x8*)(rp + ((((kg+4) ^ (px & 7)) << 3)));
        f32x4 acc = {0.f, 0.f, 0.f, 0.f};
        acc = __builtin_amdgcn_mfma_f32_16x16x32_f16(A[0], B0, acc, 0, 0, 0);
        acc = __builtin_amdgcn_mfma_f32_16x16x32_f16(A[1], B1, acc, 0, 0, 0);
        return f16x4{(f16)acc[0], (f16)acc[1], (f16)acc[2], (f16)acc[3]};
    };
    f16x4 racc0, racc1, racc2, racc3, racc4, qacc0, qacc1;
    {
        f16x8 ar[2];
        build_w(wref, ar);
        if (h == 0) {
            racc0 = proj(abuf, 0, ar); racc1 = proj(abuf, 2, ar);
            racc2 = proj(abuf, 4, ar); racc3 = proj(abuf, 6, ar);
            racc4 = proj(abuf, 8, ar);
        } else {
            racc0 = proj(abuf, 1, ar); racc1 = proj(abuf, 3, ar);
            racc2 = proj(abuf, 5, ar); racc3 = proj(abuf, 7, ar);
        }
    }
    {
        f16x8 am[2];
        build_w(wmain, am);
        if (h == 0) { qacc0 = proj(mabuf, 0, am); qacc1 = proj(mabuf, 2, am); }
        else        { qacc0 = proj(mabuf, 1, am); qacc1 = proj(mabuf, 3, am); }
    }
    __syncthreads();   // bar2: all staging reads done -> safe to overwrite

    // ---- Phase 2: write r/q in-place (lane holds d = kg*4..+3 of its pixel) ----
    auto wrout = [&](f16* dst, int t, f16x4 v) {
        int px = t * 16 + row;
        int c16 = (n << 1) | (kg >> 1);
        int off = px * 64 + (((c16 ^ (px & 7)) << 3) | ((kg & 1) << 2));
        *(f16x4*)(dst + off) = v;
    };
    if (h == 0) {
        wrout(abuf, 0, racc0); wrout(abuf, 2, racc1); wrout(abuf, 4, racc2);
        wrout(abuf, 6, racc3); wrout(abuf, 8, racc4);
        wrout(mabuf, 0, qacc0); wrout(mabuf, 2, qacc1);
    } else {
        wrout(abuf, 1, racc0); wrout(abuf, 3, racc1); wrout(abuf, 5, racc2);
        wrout(abuf, 7, racc3);
        wrout(mabuf, 1, qacc0); wrout(mabuf, 3, qacc1);
    }
    __syncthreads();   // bar3

    // ---- per-thread q fragment (pixel = lane) ----
    const int py  = l >> 3;
    const int pxx = l & 7;
    f16x8 q0 = *(const f16x8*)(mabuf + l * 64 + ((((n << 1) | 0) ^ (l & 7)) << 3));
    f16x8 q1 = *(const f16x8*)(mabuf + l * 64 + ((((n << 1) | 1) ^ (l & 7)) << 3));
    const f16x2* q2a = (const f16x2*)&q0;
    const f16x2* q2b = (const f16x2*)&q1;

    // ---- logits: half h computes 13 (or 12) offsets ----
    float lg[13];
    auto do_lg = [&](int idx, int k) {
        int ky = k / 5, kx = k % 5;              // compile-time
        int np = (py + ky) * 12 + pxx + kx;      // neighbor halo pixel
        const f16* rp = abuf + np * 64;
        f16x8 r0 = *(const f16x8*)(rp + ((((n << 1) | 0) ^ (np & 7)) << 3));
        f16x8 r1 = *(const f16x8*)(rp + ((((n << 1) | 1) ^ (np & 7)) << 3));
        const f16x2* r2a = (const f16x2*)&r0;
        const f16x2* r2b = (const f16x2*)&r1;
        float a = 0.f;
        #pragma unroll
        for (int j = 0; j < 4; ++j) a = FDOT2(q2a[j], r2a[j], a);
        #pragma unroll
        for (int j = 0; j < 4; ++j) a = FDOT2(q2b[j], r2b[j], a);
        lg[idx] = a;
    };
    if (h == 0) {
        do_lg(0,0);  do_lg(1,1);  do_lg(2,2);  do_lg(3,3);  do_lg(4,4);
        do_lg(5,5);  do_lg(6,6);  do_lg(7,7);  do_lg(8,8);  do_lg(9,9);
        do_lg(10,10); do_lg(11,11); do_lg(12,12);
    } else {
        do_lg(0,13); do_lg(1,14); do_lg(2,15); do_lg(3,16); do_lg(4,17);
        do_lg(5,18); do_lg(6,19); do_lg(7,20); do_lg(8,21); do_lg(9,22);
        do_lg(10,23); do_lg(11,24);
        lg[12] = -1e30f;   // dead slot -> exp()=0
    }

    // ---- online split softmax: single (m,s) exchange ----
    float mloc = lg[0];
    #pragma unroll
    for (int k = 1; k < 13; ++k) mloc = fmaxf(mloc, lg[k]);

    float s = 0.f;
    f16x2 pk[7];                       // exp values packed (13 -> 7 regs)
    #pragma unroll
    for (int j = 0; j < 6; ++j) {
        float e0 = __expf(lg[2*j]   - mloc);
        float e1 = __expf(lg[2*j+1] - mloc);
        s += e0 + e1;
        pk[j] = f16x2{(f16)e0, (f16)e1};
    }
    {
        float e12 = __expf(lg[12] - mloc);
        s += e12;
        pk[6] = f16x2{(f16)e12, (f16)0.f};
    }
    msbuf[(h * 4 + n) * 64 + l] = make_float2(mloc, s);
    __syncthreads();   // bar4
    float2 o = msbuf[((1 - h) * 4 + n) * 64 + l];
    float m    = fmaxf(mloc, o.x);
    float sc   = __expf(mloc - m);
    float osc  = __expf(o.x  - m);
    float inv  = sc / (s * sc + o.y * osc);

    // ---- write probs (xbuf aliases abuf/mabuf; all reads fenced by bar4) ----
    {
        float* dst = &xbuf[n * PSLAB + l * PSTRIDE + h * 13];
        #pragma unroll
        for (int j = 0; j < 6; ++j) {
            dst[2*j]     = (float)pk[j][0] * inv;
            dst[2*j + 1] = (float)pk[j][1] * inv;
        }
        if (h == 0) dst[12] = (float)pk[6][0] * inv;
    }
    __syncthreads();   // bar5

    // ---- head-average + store ----
    for (int i = tid; i < TW_ * TH_ * KK_; i += 512) {
        int p2 = i / KK_;
        int k  = i - p2 * KK_;
        int off = p2 * PSTRIDE + k;
        float v = 0.25f * (xbuf[off] + xbuf[PSLAB + off] + xbuf[2 * PSLAB + off] + xbuf[3 * PSLAB + off]);
        out[(((size_t)b * H_ + (y0 + (p2 >> 3))) * W_ + (x0 + (p2 & 7))) * KK_ + k] = v;
    }
}

extern "C" void kernel_launch(void* const* d_in, const int* in_sizes, int n_in,
                              void* d_out, int out_size, void* d_ws, size_t ws_size,
                              hipStream_t stream) {
    const float* mainp = (const float*)d_in[0];
    const float* refp  = (const float*)d_in[1];
    const float* wmain = (const float*)d_in[2];
    const float* wref  = (const float*)d_in[3];
    float* outp = (float*)d_out;

    dim3 grid(W_ / TW_, H_ / TH_, B_);
    rl8mh8<<<grid, dim3(512), 0, stream>>>(mainp, refp, wmain, wref, outp);
}